// Round 7
// baseline (240.077 us; speedup 1.0000x reference)
//
#include <hip/hip_runtime.h>
#include <stdint.h>

typedef __attribute__((ext_vector_type(8))) short short8;
typedef __attribute__((ext_vector_type(4))) float f32x4;

static __device__ __forceinline__ ushort f2bf(float f) {
  uint32_t u = __float_as_uint(f);
  uint32_t r = (u + 0x7FFFu + ((u >> 16) & 1u)) >> 16;
  return (ushort)r;
}

// ---------------------------------------------------------------------------
// KNN top-3, f64-exact selection, branchless insert. 4 threads/point.
// ---------------------------------------------------------------------------
static __device__ __forceinline__ void ins3b(double d, int i,
    double& b0, double& b1, double& b2, int& i0, int& i1, int& i2) {
  const bool c0 = d < b0, c1 = d < b1, c2 = d < b2;
  const double nb0 = c0 ? d : b0;
  const int    ni0 = c0 ? i : i0;
  const double nb1 = c0 ? b0 : (c1 ? d : b1);
  const int    ni1 = c0 ? i0 : (c1 ? i : i1);
  const double nb2 = c1 ? b1 : (c2 ? d : b2);
  const int    ni2 = c1 ? i1 : (c2 ? i : i2);
  b0 = nb0; b1 = nb1; b2 = nb2; i0 = ni0; i1 = ni1; i2 = ni2;
}

__global__ __launch_bounds__(256) void knn_kernel(
    const float* __restrict__ pos, const float* __restrict__ pos_skip,
    int4* __restrict__ idx_out, float4* __restrict__ w_out)
{
  __shared__ float pc[3072];
  const int b   = blockIdx.x >> 6;      // 64 blocks per batch
  const int blk = blockIdx.x & 63;      // 64 fine points per block
  for (int j = threadIdx.x; j < 3072; j += 256) pc[j] = pos[b * 3072 + j];
  __syncthreads();

  const int p   = threadIdx.x >> 2;     // point within block (0..63)
  const int sub = threadIdx.x & 3;      // candidate slice   (0..3)
  const int row = b * 4096 + blk * 64 + p;
  const double px = (double)pos_skip[(size_t)row * 3 + 0];
  const double py = (double)pos_skip[(size_t)row * 3 + 1];
  const double pz = (double)pos_skip[(size_t)row * 3 + 2];

  double b0 = 1e300, b1 = 1e300, b2 = 1e300;
  int i0 = 0, i1 = 0, i2 = 0;
#pragma unroll 4
  for (int j = 0; j < 256; ++j) {
    const int i = j * 4 + sub;
    const double dx = (double)pc[i * 3 + 0] - px;
    const double dy = (double)pc[i * 3 + 1] - py;
    const double dz = (double)pc[i * 3 + 2] - pz;
    const double d = dx * dx + dy * dy + dz * dz;
    ins3b(d, i, b0, b1, b2, i0, i1, i2);
  }
#pragma unroll
  for (int m = 1; m <= 2; m <<= 1) {
    const double c0 = __shfl_xor(b0, m), c1 = __shfl_xor(b1, m), c2 = __shfl_xor(b2, m);
    const int    j0 = __shfl_xor(i0, m), j1 = __shfl_xor(i1, m), j2 = __shfl_xor(i2, m);
    ins3b(c0, j0, b0, b1, b2, i0, i1, i2);
    ins3b(c1, j1, b0, b1, b2, i0, i1, i2);
    ins3b(c2, j2, b0, b1, b2, i0, i1, i2);
  }
  if (sub == 0) {
    const double w0 = 1.0 / (sqrt(b0) + 1e-8);
    const double w1 = 1.0 / (sqrt(b1) + 1e-8);
    const double w2 = 1.0 / (sqrt(b2) + 1e-8);
    const double den = w0 + w1 + w2 + 1e-8;
    idx_out[row] = make_int4(i0, i1, i2, 0);
    w_out[row] = make_float4((float)(w0 / den), (float)(w1 / den), (float)(w2 / den), 0.f);
  }
}

// ---------------------------------------------------------------------------
// Fused gather-interp + skip-copy. Depth-2 register-staged pipeline (T14):
// per row 7 named float4 loads (6 gather + 1 skip) in two ping-pong register
// sets, all statically indexed; sched_barrier(0) pins issue order so row k+1's
// loads fly while row k computes. 4 rows/wave, XCD-batch affinity kept.
// ---------------------------------------------------------------------------
struct Row7 { float4 v0, v1, v2, v3, v4, v5, v6; };

__global__ __launch_bounds__(256) void interp_gather_fused(
    const float* __restrict__ x, const float* __restrict__ xs,
    const int4* __restrict__ idx3, const float4* __restrict__ w3,
    ushort* __restrict__ hcat)
{
  const int xcd  = blockIdx.x & 7;
  const int j    = blockIdx.x >> 3;                  // 0..511 within xcd
  const int widx = j * 4 + (threadIdx.x >> 6);       // 0..2047 within xcd
  const int lane = threadIdx.x & 63;
  const int rbase = xcd * 8192 + widx * 4;           // 4 consecutive rows/wave

  int4   ids[4];
  float4 wts[4];
#pragma unroll
  for (int k = 0; k < 4; ++k) { ids[k] = idx3[rbase + k]; wts[k] = w3[rbase + k]; }

  const int b = rbase >> 12;                         // same batch for all 4 rows
  const float* xb = x + (size_t)b * 1024 * 512;

  auto loadrow = [&](int k, Row7& r) {
    const float4* f0 = (const float4*)(xb + (size_t)ids[k].x * 512);
    const float4* f1 = (const float4*)(xb + (size_t)ids[k].y * 512);
    const float4* f2 = (const float4*)(xb + (size_t)ids[k].z * 512);
    r.v0 = f0[lane]; r.v1 = f0[64 + lane];
    r.v2 = f1[lane]; r.v3 = f1[64 + lane];
    r.v4 = f2[lane]; r.v5 = f2[64 + lane];
    r.v6 = *(const float4*)(xs + (size_t)(rbase + k) * 256 + lane * 4);
  };
  auto comprow = [&](int k, const Row7& r) {
    const float4 w = wts[k];
    ushort* orow = hcat + (size_t)(rbase + k) * 768;
    float4 u;
    u.x = w.x * r.v0.x + w.y * r.v2.x + w.z * r.v4.x;
    u.y = w.x * r.v0.y + w.y * r.v2.y + w.z * r.v4.y;
    u.z = w.x * r.v0.z + w.y * r.v2.z + w.z * r.v4.z;
    u.w = w.x * r.v0.w + w.y * r.v2.w + w.z * r.v4.w;
    ushort4 o0 = { f2bf(u.x), f2bf(u.y), f2bf(u.z), f2bf(u.w) };
    *(ushort4*)(orow + lane * 4) = o0;
    u.x = w.x * r.v1.x + w.y * r.v3.x + w.z * r.v5.x;
    u.y = w.x * r.v1.y + w.y * r.v3.y + w.z * r.v5.y;
    u.z = w.x * r.v1.z + w.y * r.v3.z + w.z * r.v5.z;
    u.w = w.x * r.v1.w + w.y * r.v3.w + w.z * r.v5.w;
    ushort4 o1 = { f2bf(u.x), f2bf(u.y), f2bf(u.z), f2bf(u.w) };
    *(ushort4*)(orow + 256 + lane * 4) = o1;
    ushort4 o2 = { f2bf(r.v6.x), f2bf(r.v6.y), f2bf(r.v6.z), f2bf(r.v6.w) };
    *(ushort4*)(orow + 512 + lane * 4) = o2;
  };

  Row7 va, vb;
  loadrow(0, va);
  loadrow(1, vb);
  __builtin_amdgcn_sched_barrier(0);
  comprow(0, va);
  loadrow(2, va);
  __builtin_amdgcn_sched_barrier(0);
  comprow(1, vb);
  loadrow(3, vb);
  __builtin_amdgcn_sched_barrier(0);
  comprow(2, va);
  comprow(3, vb);
}

// Both W1 [768x512] and W2 [512x512] f32 -> transposed bf16 in one launch.
__global__ __launch_bounds__(256) void convert_wt_both(
    const float* __restrict__ W1, const float* __restrict__ W2,
    ushort* __restrict__ W1t, ushort* __restrict__ W2t)
{
  const int id = blockIdx.x * 256 + threadIdx.x;
  if (id < 768 * 512) {
    const int n = id / 768, k = id - n * 768;      // W1t[n][k] = W1[k][n]
    W1t[id] = f2bf(W1[(size_t)k * 512 + n]);
  } else {
    const int id2 = id - 768 * 512;
    if (id2 < 512 * 512) {
      const int n = id2 >> 9, k = id2 & 511;       // W2t[n][k] = W2[k][n]
      W2t[id2] = f2bf(W2[(size_t)k * 512 + n]);
    }
  }
}

// ---------------------------------------------------------------------------
// 256x256 8-phase bf16 MFMA GEMM (T1+T2+T3+T4+T5): C = relu(A*Bt^T + bias).
// 8 waves (2M x 4N), BK=64, 2-deep LDS double-buffer (128 KB), raw barriers,
// counted-vmcnt pipeline: stage t+1 issued phases 0-1, vmcnt(0) at phase-3 end.
// XOR-swizzled LDS (both-sides involution).
// ---------------------------------------------------------------------------
template<int K, bool OUT_BF16>
__global__ __launch_bounds__(512, 2) void gemm_bias_relu(
    const ushort* __restrict__ A, const ushort* __restrict__ Bt,
    const float* __restrict__ bias, void* __restrict__ Cout, int M, int N)
{
  constexpr int BM = 256, BN = 256, BK = 64, NT = K / BK;
  __shared__ ushort Asm[2][BM * BK];   // 2 x 32 KB
  __shared__ ushort Bsm[2][BN * BK];   // 2 x 32 KB
  const int tid  = threadIdx.x;
  const int lane = tid & 63;
  const int wave = tid >> 6;

  // T1: bijective XCD swizzle (gridDim.x % 8 == 0)
  const int cpx  = gridDim.x >> 3;
  const int wgid = (blockIdx.x & 7) * cpx + (blockIdx.x >> 3);
  const int nbn  = N / BN;
  const int bm   = wgid / nbn;
  const int bn   = wgid - bm * nbn;
  const int row0 = bm * BM, col0 = bn * BN;
  const int wr = wave >> 2, wc = wave & 3;     // 2M x 4N wave grid
  const int sbase = wave * 4096 + lane * 16;   // staging byte base (4KB/wave)

  f32x4 acc[8][4] = {};

  // T2 swizzle: LDS 16B slot (r, s) holds global slot (s ^ (r&7)).
  auto stageA = [&](int buf, int kt) {
#pragma unroll
    for (int i = 0; i < 4; ++i) {
      const int o = sbase + i * 1024;          // linear LDS byte offset
      const int r = o >> 7, s = (o & 127) >> 4;
      __builtin_amdgcn_global_load_lds(
          (const __attribute__((address_space(1))) void*)(A + (size_t)(row0 + r) * K + kt * BK + ((s ^ (r & 7)) << 3)),
          (__attribute__((address_space(3))) void*)((char*)&Asm[buf][0] + o), 16, 0, 0);
    }
  };
  auto stageB = [&](int buf, int kt) {
#pragma unroll
    for (int i = 0; i < 4; ++i) {
      const int o = sbase + i * 1024;
      const int r = o >> 7, s = (o & 127) >> 4;
      __builtin_amdgcn_global_load_lds(
          (const __attribute__((address_space(1))) void*)(Bt + (size_t)(col0 + r) * K + kt * BK + ((s ^ (r & 7)) << 3)),
          (__attribute__((address_space(3))) void*)((char*)&Bsm[buf][0] + o), 16, 0, 0);
    }
  };
  auto rdA = [&](int buf, int mi, int kk) -> short8 {
    const int ra = wr * 128 + mi * 16 + (lane & 15);
    const int s  = kk * 4 + (lane >> 4);
    return *(const short8*)((const char*)&Asm[buf][0] + ra * 128 + ((s ^ (ra & 7)) << 4));
  };
  auto rdB = [&](int buf, int ni, int kk) -> short8 {
    const int rb = wc * 64 + ni * 16 + (lane & 15);
    const int s  = kk * 4 + (lane >> 4);
    return *(const short8*)((const char*)&Bsm[buf][0] + rb * 128 + ((s ^ (rb & 7)) << 4));
  };

  // prologue: tile 0 fully staged and landed
  stageA(0, 0); stageB(0, 0);
  asm volatile("s_waitcnt vmcnt(0)" ::: "memory");
  __builtin_amdgcn_s_barrier();

  int cur = 0;
#pragma unroll 1
  for (int t = 0; t < NT; ++t) {
    short8 av[4], bv[4];
    // ---- phase 0: kk=0, mi 0..3 (+ stage A of t+1) ----
#pragma unroll
    for (int mi = 0; mi < 4; ++mi) av[mi] = rdA(cur, mi, 0);
#pragma unroll
    for (int ni = 0; ni < 4; ++ni) bv[ni] = rdB(cur, ni, 0);
    if (t + 1 < NT) stageA(cur ^ 1, t + 1);
    __builtin_amdgcn_s_barrier();
    asm volatile("s_waitcnt lgkmcnt(0)" ::: "memory");
    __builtin_amdgcn_sched_barrier(0);
    __builtin_amdgcn_s_setprio(1);
#pragma unroll
    for (int mi = 0; mi < 4; ++mi)
#pragma unroll
      for (int ni = 0; ni < 4; ++ni)
        acc[mi][ni] = __builtin_amdgcn_mfma_f32_16x16x32_bf16(av[mi], bv[ni], acc[mi][ni], 0, 0, 0);
    __builtin_amdgcn_s_setprio(0);
    __builtin_amdgcn_s_barrier();
    // ---- phase 1: kk=0, mi 4..7 (+ stage B of t+1) ----
#pragma unroll
    for (int mi = 0; mi < 4; ++mi) av[mi] = rdA(cur, 4 + mi, 0);
    if (t + 1 < NT) stageB(cur ^ 1, t + 1);
    __builtin_amdgcn_s_barrier();
    asm volatile("s_waitcnt lgkmcnt(0)" ::: "memory");
    __builtin_amdgcn_sched_barrier(0);
    __builtin_amdgcn_s_setprio(1);
#pragma unroll
    for (int mi = 0; mi < 4; ++mi)
#pragma unroll
      for (int ni = 0; ni < 4; ++ni)
        acc[4 + mi][ni] = __builtin_amdgcn_mfma_f32_16x16x32_bf16(av[mi], bv[ni], acc[4 + mi][ni], 0, 0, 0);
    __builtin_amdgcn_s_setprio(0);
    __builtin_amdgcn_s_barrier();
    // ---- phase 2: kk=1, mi 0..3 ----
#pragma unroll
    for (int mi = 0; mi < 4; ++mi) av[mi] = rdA(cur, mi, 1);
#pragma unroll
    for (int ni = 0; ni < 4; ++ni) bv[ni] = rdB(cur, ni, 1);
    __builtin_amdgcn_s_barrier();
    asm volatile("s_waitcnt lgkmcnt(0)" ::: "memory");
    __builtin_amdgcn_sched_barrier(0);
    __builtin_amdgcn_s_setprio(1);
#pragma unroll
    for (int mi = 0; mi < 4; ++mi)
#pragma unroll
      for (int ni = 0; ni < 4; ++ni)
        acc[mi][ni] = __builtin_amdgcn_mfma_f32_16x16x32_bf16(av[mi], bv[ni], acc[mi][ni], 0, 0, 0);
    __builtin_amdgcn_s_setprio(0);
    __builtin_amdgcn_s_barrier();
    // ---- phase 3: kk=1, mi 4..7 (+ vmcnt drain for t+1 at end) ----
#pragma unroll
    for (int mi = 0; mi < 4; ++mi) av[mi] = rdA(cur, 4 + mi, 1);
    __builtin_amdgcn_s_barrier();
    asm volatile("s_waitcnt lgkmcnt(0)" ::: "memory");
    __builtin_amdgcn_sched_barrier(0);
    __builtin_amdgcn_s_setprio(1);
#pragma unroll
    for (int mi = 0; mi < 4; ++mi)
#pragma unroll
      for (int ni = 0; ni < 4; ++ni)
        acc[4 + mi][ni] = __builtin_amdgcn_mfma_f32_16x16x32_bf16(av[mi], bv[ni], acc[4 + mi][ni], 0, 0, 0);
    __builtin_amdgcn_s_setprio(0);
    asm volatile("s_waitcnt vmcnt(0)" ::: "memory");  // t+1's stage landed
    __builtin_amdgcn_s_barrier();
    cur ^= 1;
  }

  // epilogue: bias + relu; C/D: col = lane&15, row = (lane>>4)*4 + reg
  const int lc = lane & 15, lr = lane >> 4;
#pragma unroll
  for (int mi = 0; mi < 8; ++mi) {
#pragma unroll
    for (int ni = 0; ni < 4; ++ni) {
      const int col = col0 + wc * 64 + ni * 16 + lc;
      const float bv2 = bias[col];
      const int rbase = row0 + wr * 128 + mi * 16 + lr * 4;
#pragma unroll
      for (int r = 0; r < 4; ++r) {
        float v = acc[mi][ni][r] + bv2;
        v = v > 0.f ? v : 0.f;
        if (OUT_BF16) ((ushort*)Cout)[(size_t)(rbase + r) * N + col] = f2bf(v);
        else          ((float*)Cout)[(size_t)(rbase + r) * N + col] = v;
      }
    }
  }
}

// ---------------------------------------------------------------------------
extern "C" void kernel_launch(void* const* d_in, const int* in_sizes, int n_in,
                              void* d_out, int out_size, void* d_ws, size_t ws_size,
                              hipStream_t stream) {
  const float* x        = (const float*)d_in[0];   // [16384, 512]
  const float* pos      = (const float*)d_in[1];   // [16384, 3]
  const float* x_skip   = (const float*)d_in[3];   // [65536, 256]
  const float* pos_skip = (const float*)d_in[4];   // [65536, 3]
  const float* W1       = (const float*)d_in[6];   // [768, 512]
  const float* b1       = (const float*)d_in[7];   // [512]
  const float* W2       = (const float*)d_in[8];   // [512, 512]
  const float* b2       = (const float*)d_in[9];   // [512]

  // d_out (134.2 MB f32) doubles as scratch for hcat bf16 (100.7 MB):
  // fully consumed by GEMM1 before GEMM2 overwrites d_out with the output.
  ushort* hcat = (ushort*)d_out;                       // [65536][768] bf16

  char* ws = (char*)d_ws;
  ushort* h2   = (ushort*)ws;                          // [65536][512] bf16, 67108864 B
  ushort* W1t  = (ushort*)(ws + 67108864);             // [512][768]  bf16, 786432 B
  ushort* W2t  = (ushort*)(ws + 67895296);             // [512][512]  bf16, 524288 B
  int4*   idx3 = (int4*)  (ws + 68419584);             // [65536] int4, 1 MB
  float4* w3   = (float4*)(ws + 69468160);             // [65536] float4, 1 MB

  knn_kernel<<<1024, 256, 0, stream>>>(pos, pos_skip, idx3, w3);
  convert_wt_both<<<(768 * 512 + 512 * 512 + 255) / 256, 256, 0, stream>>>(W1, W2, W1t, W2t);
  interp_gather_fused<<<4096, 256, 0, stream>>>(x, x_skip, idx3, w3, hcat);

  // GEMM1: [65536x768] x [768x512] -> h2 bf16 (ws); grid = 256 x 2 = 512
  gemm_bias_relu<768, true><<<512, 512, 0, stream>>>(hcat, W1t, b1, (void*)h2, 65536, 512);
  // GEMM2: [65536x512] x [512x512] -> d_out f32
  gemm_bias_relu<512, false><<<512, 512, 0, stream>>>(h2, W2t, b2, d_out, 65536, 512);
}

// Round 8
// 234.498 us; speedup vs baseline: 1.0238x; 1.0238x over previous
//
#include <hip/hip_runtime.h>
#include <stdint.h>

typedef __attribute__((ext_vector_type(8))) short short8;
typedef __attribute__((ext_vector_type(4))) float f32x4;

static __device__ __forceinline__ ushort f2bf(float f) {
  uint32_t u = __float_as_uint(f);
  uint32_t r = (u + 0x7FFFu + ((u >> 16) & 1u)) >> 16;
  return (ushort)r;
}
static __device__ __forceinline__ float bf2f(ushort h) {
  return __uint_as_float(((uint32_t)h) << 16);
}

// ---------------------------------------------------------------------------
// KNN top-3, f64-exact selection, branchless insert. 4 threads/point.
// ---------------------------------------------------------------------------
static __device__ __forceinline__ void ins3b(double d, int i,
    double& b0, double& b1, double& b2, int& i0, int& i1, int& i2) {
  const bool c0 = d < b0, c1 = d < b1, c2 = d < b2;
  const double nb0 = c0 ? d : b0;
  const int    ni0 = c0 ? i : i0;
  const double nb1 = c0 ? b0 : (c1 ? d : b1);
  const int    ni1 = c0 ? i0 : (c1 ? i : i1);
  const double nb2 = c1 ? b1 : (c2 ? d : b2);
  const int    ni2 = c1 ? i1 : (c2 ? i : i2);
  b0 = nb0; b1 = nb1; b2 = nb2; i0 = ni0; i1 = ni1; i2 = ni2;
}

__global__ __launch_bounds__(256) void knn_kernel(
    const float* __restrict__ pos, const float* __restrict__ pos_skip,
    int4* __restrict__ idx_out, float4* __restrict__ w_out)
{
  __shared__ float pc[3072];
  const int b   = blockIdx.x >> 6;      // 64 blocks per batch
  const int blk = blockIdx.x & 63;      // 64 fine points per block
  for (int j = threadIdx.x; j < 3072; j += 256) pc[j] = pos[b * 3072 + j];
  __syncthreads();

  const int p   = threadIdx.x >> 2;     // point within block (0..63)
  const int sub = threadIdx.x & 3;      // candidate slice   (0..3)
  const int row = b * 4096 + blk * 64 + p;
  const double px = (double)pos_skip[(size_t)row * 3 + 0];
  const double py = (double)pos_skip[(size_t)row * 3 + 1];
  const double pz = (double)pos_skip[(size_t)row * 3 + 2];

  double b0 = 1e300, b1 = 1e300, b2 = 1e300;
  int i0 = 0, i1 = 0, i2 = 0;
#pragma unroll 4
  for (int j = 0; j < 256; ++j) {
    const int i = j * 4 + sub;
    const double dx = (double)pc[i * 3 + 0] - px;
    const double dy = (double)pc[i * 3 + 1] - py;
    const double dz = (double)pc[i * 3 + 2] - pz;
    const double d = dx * dx + dy * dy + dz * dz;
    ins3b(d, i, b0, b1, b2, i0, i1, i2);
  }
#pragma unroll
  for (int m = 1; m <= 2; m <<= 1) {
    const double c0 = __shfl_xor(b0, m), c1 = __shfl_xor(b1, m), c2 = __shfl_xor(b2, m);
    const int    j0 = __shfl_xor(i0, m), j1 = __shfl_xor(i1, m), j2 = __shfl_xor(i2, m);
    ins3b(c0, j0, b0, b1, b2, i0, i1, i2);
    ins3b(c1, j1, b0, b1, b2, i0, i1, i2);
    ins3b(c2, j2, b0, b1, b2, i0, i1, i2);
  }
  if (sub == 0) {
    const double w0 = 1.0 / (sqrt(b0) + 1e-8);
    const double w1 = 1.0 / (sqrt(b1) + 1e-8);
    const double w2 = 1.0 / (sqrt(b2) + 1e-8);
    const double den = w0 + w1 + w2 + 1e-8;
    idx_out[row] = make_int4(i0, i1, i2, 0);
    w_out[row] = make_float4((float)(w0 / den), (float)(w1 / den), (float)(w2 / den), 0.f);
  }
}

// x f32 [16384][512] -> bf16 [16384][512]; halves gather volume and makes the
// per-XCD interp working set (2 batches = 2.1 MB) L2-resident.
__global__ __launch_bounds__(256) void convert_x(
    const float* __restrict__ x, ushort* __restrict__ xbf)
{
  const int id = blockIdx.x * 256 + threadIdx.x;   // one float4 each
#pragma unroll
  for (int it = 0; it < 4; ++it) {
    const int i = id + it * 524288;                // 2097152 float4s total
    const float4 v = *(const float4*)(x + (size_t)i * 4);
    ushort4 o = { f2bf(v.x), f2bf(v.y), f2bf(v.z), f2bf(v.w) };
    *(ushort4*)(xbf + (size_t)i * 4) = o;
  }
}

// ---------------------------------------------------------------------------
// Fused gather-interp (bf16 gathers) + skip-copy. Depth-2 register pipeline,
// 4 rows/wave, XCD-batch affinity. Per row: 3 short8 gathers + 1 xs float4.
// ---------------------------------------------------------------------------
struct Row4 { short8 g0, g1, g2; float4 s; };

__global__ __launch_bounds__(256) void interp_gather_fused(
    const ushort* __restrict__ xbf, const float* __restrict__ xs,
    const int4* __restrict__ idx3, const float4* __restrict__ w3,
    ushort* __restrict__ hcat)
{
  const int xcd  = blockIdx.x & 7;
  const int j    = blockIdx.x >> 3;                  // 0..511 within xcd
  const int widx = j * 4 + (threadIdx.x >> 6);       // 0..2047 within xcd
  const int lane = threadIdx.x & 63;
  const int rbase = xcd * 8192 + widx * 4;           // 4 consecutive rows/wave

  int4   ids[4];
  float4 wts[4];
#pragma unroll
  for (int k = 0; k < 4; ++k) { ids[k] = idx3[rbase + k]; wts[k] = w3[rbase + k]; }

  const int b = rbase >> 12;                         // same batch for all 4 rows
  const ushort* xb = xbf + (size_t)b * 1024 * 512;

  auto loadrow = [&](int k, Row4& r) {
    r.g0 = *(const short8*)(xb + (size_t)ids[k].x * 512 + lane * 8);
    r.g1 = *(const short8*)(xb + (size_t)ids[k].y * 512 + lane * 8);
    r.g2 = *(const short8*)(xb + (size_t)ids[k].z * 512 + lane * 8);
    r.s  = *(const float4*)(xs + (size_t)(rbase + k) * 256 + lane * 4);
  };
  auto comprow = [&](int k, const Row4& r) {
    const float4 w = wts[k];
    ushort* orow = hcat + (size_t)(rbase + k) * 768;
    short8 o;
#pragma unroll
    for (int e = 0; e < 8; ++e) {
      const float v = w.x * bf2f((ushort)r.g0[e])
                    + w.y * bf2f((ushort)r.g1[e])
                    + w.z * bf2f((ushort)r.g2[e]);
      o[e] = (short)f2bf(v);
    }
    *(short8*)(orow + lane * 8) = o;
    ushort4 o2 = { f2bf(r.s.x), f2bf(r.s.y), f2bf(r.s.z), f2bf(r.s.w) };
    *(ushort4*)(orow + 512 + lane * 4) = o2;
  };

  Row4 va, vb;
  loadrow(0, va);
  loadrow(1, vb);
  __builtin_amdgcn_sched_barrier(0);
  comprow(0, va);
  loadrow(2, va);
  __builtin_amdgcn_sched_barrier(0);
  comprow(1, vb);
  loadrow(3, vb);
  __builtin_amdgcn_sched_barrier(0);
  comprow(2, va);
  comprow(3, vb);
}

// Both W1 [768x512] and W2 [512x512] f32 -> transposed bf16 in one launch.
__global__ __launch_bounds__(256) void convert_wt_both(
    const float* __restrict__ W1, const float* __restrict__ W2,
    ushort* __restrict__ W1t, ushort* __restrict__ W2t)
{
  const int id = blockIdx.x * 256 + threadIdx.x;
  if (id < 768 * 512) {
    const int n = id / 768, k = id - n * 768;      // W1t[n][k] = W1[k][n]
    W1t[id] = f2bf(W1[(size_t)k * 512 + n]);
  } else {
    const int id2 = id - 768 * 512;
    if (id2 < 512 * 512) {
      const int n = id2 >> 9, k = id2 & 511;       // W2t[n][k] = W2[k][n]
      W2t[id2] = f2bf(W2[(size_t)k * 512 + n]);
    }
  }
}

// ---------------------------------------------------------------------------
// 256x256 8-phase bf16 MFMA GEMM (T1+T2+T3+T4+T5): C = relu(A*Bt^T + bias).
// 8 waves (2M x 4N), BK=64, 2-deep LDS double-buffer (128 KB), raw barriers,
// counted-vmcnt pipeline. XOR-swizzled LDS (both-sides involution).
// ---------------------------------------------------------------------------
template<int K, bool OUT_BF16>
__global__ __launch_bounds__(512, 2) void gemm_bias_relu(
    const ushort* __restrict__ A, const ushort* __restrict__ Bt,
    const float* __restrict__ bias, void* __restrict__ Cout, int M, int N)
{
  constexpr int BM = 256, BN = 256, BK = 64, NT = K / BK;
  __shared__ ushort Asm[2][BM * BK];   // 2 x 32 KB
  __shared__ ushort Bsm[2][BN * BK];   // 2 x 32 KB
  const int tid  = threadIdx.x;
  const int lane = tid & 63;
  const int wave = tid >> 6;

  // T1: bijective XCD swizzle (gridDim.x % 8 == 0)
  const int cpx  = gridDim.x >> 3;
  const int wgid = (blockIdx.x & 7) * cpx + (blockIdx.x >> 3);
  const int nbn  = N / BN;
  const int bm   = wgid / nbn;
  const int bn   = wgid - bm * nbn;
  const int row0 = bm * BM, col0 = bn * BN;
  const int wr = wave >> 2, wc = wave & 3;     // 2M x 4N wave grid
  const int sbase = wave * 4096 + lane * 16;   // staging byte base (4KB/wave)

  f32x4 acc[8][4] = {};

  // T2 swizzle: LDS 16B slot (r, s) holds global slot (s ^ (r&7)).
  auto stageA = [&](int buf, int kt) {
#pragma unroll
    for (int i = 0; i < 4; ++i) {
      const int o = sbase + i * 1024;          // linear LDS byte offset
      const int r = o >> 7, s = (o & 127) >> 4;
      __builtin_amdgcn_global_load_lds(
          (const __attribute__((address_space(1))) void*)(A + (size_t)(row0 + r) * K + kt * BK + ((s ^ (r & 7)) << 3)),
          (__attribute__((address_space(3))) void*)((char*)&Asm[buf][0] + o), 16, 0, 0);
    }
  };
  auto stageB = [&](int buf, int kt) {
#pragma unroll
    for (int i = 0; i < 4; ++i) {
      const int o = sbase + i * 1024;
      const int r = o >> 7, s = (o & 127) >> 4;
      __builtin_amdgcn_global_load_lds(
          (const __attribute__((address_space(1))) void*)(Bt + (size_t)(col0 + r) * K + kt * BK + ((s ^ (r & 7)) << 3)),
          (__attribute__((address_space(3))) void*)((char*)&Bsm[buf][0] + o), 16, 0, 0);
    }
  };
  auto rdA = [&](int buf, int mi, int kk) -> short8 {
    const int ra = wr * 128 + mi * 16 + (lane & 15);
    const int s  = kk * 4 + (lane >> 4);
    return *(const short8*)((const char*)&Asm[buf][0] + ra * 128 + ((s ^ (ra & 7)) << 4));
  };
  auto rdB = [&](int buf, int ni, int kk) -> short8 {
    const int rb = wc * 64 + ni * 16 + (lane & 15);
    const int s  = kk * 4 + (lane >> 4);
    return *(const short8*)((const char*)&Bsm[buf][0] + rb * 128 + ((s ^ (rb & 7)) << 4));
  };

  // prologue: tile 0 fully staged and landed
  stageA(0, 0); stageB(0, 0);
  asm volatile("s_waitcnt vmcnt(0)" ::: "memory");
  __builtin_amdgcn_s_barrier();

  int cur = 0;
#pragma unroll 1
  for (int t = 0; t < NT; ++t) {
    short8 av[4], bv[4];
    // ---- phase 0: kk=0, mi 0..3 (+ stage A of t+1) ----
#pragma unroll
    for (int mi = 0; mi < 4; ++mi) av[mi] = rdA(cur, mi, 0);
#pragma unroll
    for (int ni = 0; ni < 4; ++ni) bv[ni] = rdB(cur, ni, 0);
    if (t + 1 < NT) stageA(cur ^ 1, t + 1);
    __builtin_amdgcn_s_barrier();
    asm volatile("s_waitcnt lgkmcnt(0)" ::: "memory");
    __builtin_amdgcn_sched_barrier(0);
    __builtin_amdgcn_s_setprio(1);
#pragma unroll
    for (int mi = 0; mi < 4; ++mi)
#pragma unroll
      for (int ni = 0; ni < 4; ++ni)
        acc[mi][ni] = __builtin_amdgcn_mfma_f32_16x16x32_bf16(av[mi], bv[ni], acc[mi][ni], 0, 0, 0);
    __builtin_amdgcn_s_setprio(0);
    __builtin_amdgcn_s_barrier();
    // ---- phase 1: kk=0, mi 4..7 (+ stage B of t+1) ----
#pragma unroll
    for (int mi = 0; mi < 4; ++mi) av[mi] = rdA(cur, 4 + mi, 0);
    if (t + 1 < NT) stageB(cur ^ 1, t + 1);
    __builtin_amdgcn_s_barrier();
    asm volatile("s_waitcnt lgkmcnt(0)" ::: "memory");
    __builtin_amdgcn_sched_barrier(0);
    __builtin_amdgcn_s_setprio(1);
#pragma unroll
    for (int mi = 0; mi < 4; ++mi)
#pragma unroll
      for (int ni = 0; ni < 4; ++ni)
        acc[4 + mi][ni] = __builtin_amdgcn_mfma_f32_16x16x32_bf16(av[mi], bv[ni], acc[4 + mi][ni], 0, 0, 0);
    __builtin_amdgcn_s_setprio(0);
    __builtin_amdgcn_s_barrier();
    // ---- phase 2: kk=1, mi 0..3 ----
#pragma unroll
    for (int mi = 0; mi < 4; ++mi) av[mi] = rdA(cur, mi, 1);
#pragma unroll
    for (int ni = 0; ni < 4; ++ni) bv[ni] = rdB(cur, ni, 1);
    __builtin_amdgcn_s_barrier();
    asm volatile("s_waitcnt lgkmcnt(0)" ::: "memory");
    __builtin_amdgcn_sched_barrier(0);
    __builtin_amdgcn_s_setprio(1);
#pragma unroll
    for (int mi = 0; mi < 4; ++mi)
#pragma unroll
      for (int ni = 0; ni < 4; ++ni)
        acc[mi][ni] = __builtin_amdgcn_mfma_f32_16x16x32_bf16(av[mi], bv[ni], acc[mi][ni], 0, 0, 0);
    __builtin_amdgcn_s_setprio(0);
    __builtin_amdgcn_s_barrier();
    // ---- phase 3: kk=1, mi 4..7 (+ vmcnt drain for t+1 at end) ----
#pragma unroll
    for (int mi = 0; mi < 4; ++mi) av[mi] = rdA(cur, 4 + mi, 1);
    __builtin_amdgcn_s_barrier();
    asm volatile("s_waitcnt lgkmcnt(0)" ::: "memory");
    __builtin_amdgcn_sched_barrier(0);
    __builtin_amdgcn_s_setprio(1);
#pragma unroll
    for (int mi = 0; mi < 4; ++mi)
#pragma unroll
      for (int ni = 0; ni < 4; ++ni)
        acc[4 + mi][ni] = __builtin_amdgcn_mfma_f32_16x16x32_bf16(av[mi], bv[ni], acc[4 + mi][ni], 0, 0, 0);
    __builtin_amdgcn_s_setprio(0);
    asm volatile("s_waitcnt vmcnt(0)" ::: "memory");  // t+1's stage landed
    __builtin_amdgcn_s_barrier();
    cur ^= 1;
  }

  // epilogue: bias + relu; C/D: col = lane&15, row = (lane>>4)*4 + reg
  const int lc = lane & 15, lr = lane >> 4;
#pragma unroll
  for (int mi = 0; mi < 8; ++mi) {
#pragma unroll
    for (int ni = 0; ni < 4; ++ni) {
      const int col = col0 + wc * 64 + ni * 16 + lc;
      const float bv2 = bias[col];
      const int rbase = row0 + wr * 128 + mi * 16 + lr * 4;
#pragma unroll
      for (int r = 0; r < 4; ++r) {
        float v = acc[mi][ni][r] + bv2;
        v = v > 0.f ? v : 0.f;
        if (OUT_BF16) ((ushort*)Cout)[(size_t)(rbase + r) * N + col] = f2bf(v);
        else          ((float*)Cout)[(size_t)(rbase + r) * N + col] = v;
      }
    }
  }
}

// ---------------------------------------------------------------------------
extern "C" void kernel_launch(void* const* d_in, const int* in_sizes, int n_in,
                              void* d_out, int out_size, void* d_ws, size_t ws_size,
                              hipStream_t stream) {
  const float* x        = (const float*)d_in[0];   // [16384, 512]
  const float* pos      = (const float*)d_in[1];   // [16384, 3]
  const float* x_skip   = (const float*)d_in[3];   // [65536, 256]
  const float* pos_skip = (const float*)d_in[4];   // [65536, 3]
  const float* W1       = (const float*)d_in[6];   // [768, 512]
  const float* b1       = (const float*)d_in[7];   // [512]
  const float* W2       = (const float*)d_in[8];   // [512, 512]
  const float* b2       = (const float*)d_in[9];   // [512]

  // d_out (134.2 MB f32) doubles as scratch: hcat bf16 (100.7 MB) + xbf bf16
  // (16.8 MB in the tail). Both fully consumed before GEMM2 overwrites d_out.
  ushort* hcat = (ushort*)d_out;                       // [65536][768] bf16
  ushort* xbf  = (ushort*)((char*)d_out + 100663296);  // [16384][512] bf16

  char* ws = (char*)d_ws;
  ushort* h2   = (ushort*)ws;                          // [65536][512] bf16, 67108864 B
  ushort* W1t  = (ushort*)(ws + 67108864);             // [512][768]  bf16, 786432 B
  ushort* W2t  = (ushort*)(ws + 67895296);             // [512][512]  bf16, 524288 B
  int4*   idx3 = (int4*)  (ws + 68419584);             // [65536] int4, 1 MB
  float4* w3   = (float4*)(ws + 69468160);             // [65536] float4, 1 MB

  knn_kernel<<<1024, 256, 0, stream>>>(pos, pos_skip, idx3, w3);
  convert_x<<<2048, 256, 0, stream>>>(x, xbf);
  convert_wt_both<<<(768 * 512 + 512 * 512 + 255) / 256, 256, 0, stream>>>(W1, W2, W1t, W2t);
  interp_gather_fused<<<4096, 256, 0, stream>>>(xbf, x_skip, idx3, w3, hcat);

  // GEMM1: [65536x768] x [768x512] -> h2 bf16 (ws); grid = 256 x 2 = 512
  gemm_bias_relu<768, true><<<512, 512, 0, stream>>>(hcat, W1t, b1, (void*)h2, 65536, 512);
  // GEMM2: [65536x512] x [512x512] -> d_out f32
  gemm_bias_relu<512, false><<<512, 512, 0, stream>>>(h2, W2t, b2, d_out, 65536, 512);
}